// Round 6
// baseline (36.836 us; speedup 1.0000x reference)
//
#include <hip/hip_runtime.h>

#define IMG_H 512
#define IMG_W 512
#define MAX_STREAKS 64
#define ROWS_PER_BLOCK 8       // 8 rows * 512 cols = 4096 scalars = 1024 float4
#define SLICES_PER_BLOCK 4     // each block streams 4 (b,c) slices with one prologue

typedef float v4f __attribute__((ext_vector_type(4)));
typedef int   v4i __attribute__((ext_vector_type(4)));

__device__ __forceinline__ v4f blend4(v4f xv, v4f fv) {
    v4f o;
    o.x = fminf(fmaxf(fmaf(xv.x, fv.x, 1.0f - fv.x), 0.0f), 1.0f);
    o.y = fminf(fmaxf(fmaf(xv.y, fv.y, 1.0f - fv.y), 0.0f), 1.0f);
    o.z = fminf(fmaxf(fmaf(xv.z, fv.z, 1.0f - fv.z), 0.0f), 1.0f);
    o.w = fminf(fmaxf(fmaf(xv.w, fv.w, 1.0f - fv.w), 0.0f), 1.0f);
    return o;
}

// Fused rain streaks:
//  - per block: rasterize overlap counts for its 8 image rows into LDS
//    (O(streaks) atomics), convert to f=(1-a)^k (vectorized), load the f-tile
//    into registers, then stream x->out for 4 (b,c) slices reusing the f regs.
//  - x loads cached (L3-resident across graph replays); out stores nontemporal
//    (write-only; don't evict x from L3).
__global__ void __launch_bounds__(256)
rain_fused_kernel(const v4f* __restrict__ x,
                  const float* __restrict__ alpha,
                  const int* __restrict__ xc,
                  const int* __restrict__ y0,
                  const int* __restrict__ y1_off,
                  v4f* __restrict__ out,
                  int n_streaks) {
    __shared__ int s_xc[MAX_STREAKS], s_y0[MAX_STREAKS], s_y1[MAX_STREAKS];
    __shared__ float s_f[ROWS_PER_BLOCK][IMG_W];        // 16 KB; counts during build
    v4f* s_f4 = (v4f*)&s_f[0][0];                       // 1024 entries
    int* s_hist = (int*)&s_f[0][0];

    const int tid = threadIdx.x;
    if (tid < n_streaks) {
        s_xc[tid] = xc[tid];
        s_y0[tid] = y0[tid];
        s_y1[tid] = y1_off[tid] + IMG_H / 2;
    }
    // Zero the count tile, vectorized (4 passes of b128 writes).
    #pragma unroll
    for (int i = tid; i < ROWS_PER_BLOCK * IMG_W / 4; i += 256) {
        v4f z = {0.0f, 0.0f, 0.0f, 0.0f};               // bit pattern == int 0
        s_f4[i] = z;
    }
    __syncthreads();

    const int rc = blockIdx.x & 63;                     // row-chunk [0,64)
    const int grp = blockIdx.x >> 6;                    // slice group [0,24)
    const int hbase = rc * ROWS_PER_BLOCK;

    // Rasterize: one (row, streak) pair per work item; each streak touches
    // at most 2 columns of a row.
    for (int p = tid; p < (n_streaks << 3); p += 256) {
        int r = p & 7, s = p >> 3;
        int h = hbase + r;
        if (h >= s_y0[s] && h < s_y1[s]) {
            int c = s_xc[s];
            atomicAdd(&s_hist[(r << 9) + (c - 1 > 0 ? c - 1 : 0)], 1);
            if (c >= 1) atomicAdd(&s_hist[(r << 9) + c], 1);
        }
    }
    __syncthreads();

    // Convert count -> factor, vectorized b128 read/modify/write (owned slots).
    const float l2f = __log2f(1.0f - alpha[0]);
    #pragma unroll
    for (int i = tid; i < ROWS_PER_BLOCK * IMG_W / 4; i += 256) {
        v4i kv = *(v4i*)&s_f4[i];
        v4f fv;
        fv.x = exp2f(l2f * (float)kv.x);                // k==0 -> exactly 1.0f
        fv.y = exp2f(l2f * (float)kv.y);
        fv.z = exp2f(l2f * (float)kv.z);
        fv.w = exp2f(l2f * (float)kv.w);
        s_f4[i] = fv;
    }
    __syncthreads();

    // Hoist this thread's 4 f-values into registers; reuse across all slices.
    v4f f0 = s_f4[tid];
    v4f f1 = s_f4[256 + tid];
    v4f f2 = s_f4[512 + tid];
    v4f f3 = s_f4[768 + tid];

    // Stream 4 slices: same 8 rows, (b,c) = grp*4 .. grp*4+3.
    const size_t base = (size_t)grp * SLICES_PER_BLOCK * (IMG_H * IMG_W / 4)
                      + (size_t)rc * (ROWS_PER_BLOCK * IMG_W / 4);
    #pragma unroll
    for (int j = 0; j < SLICES_PER_BLOCK; ++j) {
        const v4f* xb = x   + base + (size_t)j * (IMG_H * IMG_W / 4);
        v4f*       ob = out + base + (size_t)j * (IMG_H * IMG_W / 4);
        v4f x0 = xb[tid];
        v4f x1 = xb[256 + tid];
        v4f x2 = xb[512 + tid];
        v4f x3 = xb[768 + tid];
        __builtin_nontemporal_store(blend4(x0, f0), &ob[tid]);
        __builtin_nontemporal_store(blend4(x1, f1), &ob[256 + tid]);
        __builtin_nontemporal_store(blend4(x2, f2), &ob[512 + tid]);
        __builtin_nontemporal_store(blend4(x3, f3), &ob[768 + tid]);
    }
}

extern "C" void kernel_launch(void* const* d_in, const int* in_sizes, int n_in,
                              void* d_out, int out_size, void* d_ws, size_t ws_size,
                              hipStream_t stream) {
    const float* x      = (const float*)d_in[0];
    const float* alpha  = (const float*)d_in[1];
    const int*   xc     = (const int*)d_in[2];
    const int*   y0     = (const int*)d_in[3];
    const int*   y1_off = (const int*)d_in[4];
    float* out = (float*)d_out;

    int n_streaks = in_sizes[2];

    // out_size = 32*3*512*512 = 25,165,824 scalars.
    // Per block: 8 rows * 512 cols * 4 slices = 16384 scalars -> 1536 blocks.
    int blocks = out_size / (ROWS_PER_BLOCK * IMG_W * SLICES_PER_BLOCK);
    rain_fused_kernel<<<blocks, 256, 0, stream>>>(
        (const v4f*)x, alpha, xc, y0, y1_off, (v4f*)out, n_streaks);
}

// Round 7
// 36.045 us; speedup vs baseline: 1.0220x; 1.0220x over previous
//
#include <hip/hip_runtime.h>

#define IMG_H 512
#define IMG_W 512
#define MAX_STREAKS 64
#define ROWS_PER_BLOCK 8   // 8 rows * 512 cols = 4096 scalars = 1024 float4 per block

typedef float v4f __attribute__((ext_vector_type(4)));
typedef int   v4i __attribute__((ext_vector_type(4)));

__device__ __forceinline__ v4f blend4(v4f xv, v4f fv) {
    v4f o;
    o.x = fminf(fmaxf(fmaf(xv.x, fv.x, 1.0f - fv.x), 0.0f), 1.0f);
    o.y = fminf(fmaxf(fmaf(xv.y, fv.y, 1.0f - fv.y), 0.0f), 1.0f);
    o.z = fminf(fmaxf(fmaf(xv.z, fv.z, 1.0f - fv.z), 0.0f), 1.0f);
    o.w = fminf(fmaxf(fmaf(xv.w, fv.w, 1.0f - fv.w), 0.0f), 1.0f);
    return o;
}

// Fused rain streaks, async-staged:
//  1. issue this thread's 4 global x loads FIRST (HBM latency hides under prologue)
//  2. prologue: rasterize overlap counts for the block's 8 rows into LDS
//     (O(streaks) atomics), convert to f=(1-a)^k in place (vectorized)
//  3. blend loaded x with f from LDS, nontemporal store (write-only out must
//     not evict x from the memory-side cache).
__global__ void __launch_bounds__(256, 8)
rain_fused_kernel(const v4f* __restrict__ x,
                  const float* __restrict__ alpha,
                  const int* __restrict__ xc,
                  const int* __restrict__ y0,
                  const int* __restrict__ y1_off,
                  v4f* __restrict__ out,
                  int n_streaks) {
    __shared__ int s_xc[MAX_STREAKS], s_y0[MAX_STREAKS], s_y1[MAX_STREAKS];
    __shared__ float s_f[ROWS_PER_BLOCK][IMG_W];        // 16 KB; counts during build
    v4f* s_f4 = (v4f*)&s_f[0][0];                       // 1024 entries
    int* s_hist = (int*)&s_f[0][0];

    const int tid = threadIdx.x;

    // --- 1. issue global loads before any LDS traffic ---
    const v4f* xb = x + (size_t)blockIdx.x * 1024;
    v4f*       ob = out + (size_t)blockIdx.x * 1024;
    v4f x0 = xb[tid];
    v4f x1 = xb[256 + tid];
    v4f x2 = xb[512 + tid];
    v4f x3 = xb[768 + tid];

    // --- 2. prologue ---
    if (tid < n_streaks) {
        s_xc[tid] = xc[tid];
        s_y0[tid] = y0[tid];
        s_y1[tid] = y1_off[tid] + IMG_H / 2;
    }
    #pragma unroll
    for (int i = tid; i < ROWS_PER_BLOCK * IMG_W / 4; i += 256) {
        v4f z = {0.0f, 0.0f, 0.0f, 0.0f};               // bit pattern == int 0
        s_f4[i] = z;
    }
    __syncthreads();

    const int hbase = (blockIdx.x & 63) * ROWS_PER_BLOCK;  // row-chunk

    // Rasterize: one (row, streak) pair per work item; each streak touches
    // at most 2 columns of a row.
    for (int p = tid; p < (n_streaks << 3); p += 256) {
        int r = p & 7, s = p >> 3;
        int h = hbase + r;
        if (h >= s_y0[s] && h < s_y1[s]) {
            int c = s_xc[s];
            atomicAdd(&s_hist[(r << 9) + (c - 1 > 0 ? c - 1 : 0)], 1);
            if (c >= 1) atomicAdd(&s_hist[(r << 9) + c], 1);
        }
    }
    __syncthreads();

    // Convert count -> factor, vectorized b128 read/modify/write (owned slots).
    const float l2f = __log2f(1.0f - alpha[0]);
    #pragma unroll
    for (int i = tid; i < ROWS_PER_BLOCK * IMG_W / 4; i += 256) {
        v4i kv = *(v4i*)&s_f4[i];
        v4f fv;
        fv.x = exp2f(l2f * (float)kv.x);                // k==0 -> exactly 1.0f
        fv.y = exp2f(l2f * (float)kv.y);
        fv.z = exp2f(l2f * (float)kv.z);
        fv.w = exp2f(l2f * (float)kv.w);
        s_f4[i] = fv;
    }
    __syncthreads();

    // --- 3. blend + stream out ---
    v4f f0 = s_f4[tid];
    v4f f1 = s_f4[256 + tid];
    v4f f2 = s_f4[512 + tid];
    v4f f3 = s_f4[768 + tid];

    __builtin_nontemporal_store(blend4(x0, f0), &ob[tid]);
    __builtin_nontemporal_store(blend4(x1, f1), &ob[256 + tid]);
    __builtin_nontemporal_store(blend4(x2, f2), &ob[512 + tid]);
    __builtin_nontemporal_store(blend4(x3, f3), &ob[768 + tid]);
}

extern "C" void kernel_launch(void* const* d_in, const int* in_sizes, int n_in,
                              void* d_out, int out_size, void* d_ws, size_t ws_size,
                              hipStream_t stream) {
    const float* x      = (const float*)d_in[0];
    const float* alpha  = (const float*)d_in[1];
    const int*   xc     = (const int*)d_in[2];
    const int*   y0     = (const int*)d_in[3];
    const int*   y1_off = (const int*)d_in[4];
    float* out = (float*)d_out;

    int n_streaks = in_sizes[2];

    // out_size = 32*3*512*512 = 25,165,824 scalars; 4096 per block -> 6144 blocks.
    int blocks = out_size / (ROWS_PER_BLOCK * IMG_W);
    rain_fused_kernel<<<blocks, 256, 0, stream>>>(
        (const v4f*)x, alpha, xc, y0, y1_off, (v4f*)out, n_streaks);
}

// Round 8
// 35.231 us; speedup vs baseline: 1.0456x; 1.0231x over previous
//
#include <hip/hip_runtime.h>

#define IMG_H 512
#define IMG_W 512
#define MAX_STREAKS 64
#define ROWS_PER_BLOCK 8   // 8 rows * 512 cols = 4096 scalars = 1024 float4 per block

typedef float v4f __attribute__((ext_vector_type(4)));
typedef int   v4i __attribute__((ext_vector_type(4)));

__device__ __forceinline__ v4f blend4(v4f xv, v4f fv) {
    v4f o;
    o.x = fminf(fmaxf(fmaf(xv.x, fv.x, 1.0f - fv.x), 0.0f), 1.0f);
    o.y = fminf(fmaxf(fmaf(xv.y, fv.y, 1.0f - fv.y), 0.0f), 1.0f);
    o.z = fminf(fmaxf(fmaf(xv.z, fv.z, 1.0f - fv.z), 0.0f), 1.0f);
    o.w = fminf(fmaxf(fmaf(xv.w, fv.w, 1.0f - fv.w), 0.0f), 1.0f);
    return o;
}

// Fused rain streaks, async-staged:
//  1. issue this thread's 4 global x loads FIRST (HBM latency hides under prologue)
//  2. prologue: rasterize overlap counts for the block's 8 rows into LDS
//     (O(streaks) atomics), convert to f=(1-a)^k in place (vectorized)
//  3. blend loaded x with f from LDS, PLAIN store — A/B vs round 7's nt-store:
//     x(100MB)+out(98MB) nearly fits the 256MB L3; letting out allocate may
//     keep both resident across graph replays (no re-poison between replays),
//     turning x reads into L3 hits.
__global__ void __launch_bounds__(256, 8)
rain_fused_kernel(const v4f* __restrict__ x,
                  const float* __restrict__ alpha,
                  const int* __restrict__ xc,
                  const int* __restrict__ y0,
                  const int* __restrict__ y1_off,
                  v4f* __restrict__ out,
                  int n_streaks) {
    __shared__ int s_xc[MAX_STREAKS], s_y0[MAX_STREAKS], s_y1[MAX_STREAKS];
    __shared__ float s_f[ROWS_PER_BLOCK][IMG_W];        // 16 KB; counts during build
    v4f* s_f4 = (v4f*)&s_f[0][0];                       // 1024 entries
    int* s_hist = (int*)&s_f[0][0];

    const int tid = threadIdx.x;

    // --- 1. issue global loads before any LDS traffic ---
    const v4f* xb = x + (size_t)blockIdx.x * 1024;
    v4f*       ob = out + (size_t)blockIdx.x * 1024;
    v4f x0 = xb[tid];
    v4f x1 = xb[256 + tid];
    v4f x2 = xb[512 + tid];
    v4f x3 = xb[768 + tid];

    // --- 2. prologue ---
    if (tid < n_streaks) {
        s_xc[tid] = xc[tid];
        s_y0[tid] = y0[tid];
        s_y1[tid] = y1_off[tid] + IMG_H / 2;
    }
    #pragma unroll
    for (int i = tid; i < ROWS_PER_BLOCK * IMG_W / 4; i += 256) {
        v4f z = {0.0f, 0.0f, 0.0f, 0.0f};               // bit pattern == int 0
        s_f4[i] = z;
    }
    __syncthreads();

    const int hbase = (blockIdx.x & 63) * ROWS_PER_BLOCK;  // row-chunk

    // Rasterize: one (row, streak) pair per work item; each streak touches
    // at most 2 columns of a row.
    for (int p = tid; p < (n_streaks << 3); p += 256) {
        int r = p & 7, s = p >> 3;
        int h = hbase + r;
        if (h >= s_y0[s] && h < s_y1[s]) {
            int c = s_xc[s];
            atomicAdd(&s_hist[(r << 9) + (c - 1 > 0 ? c - 1 : 0)], 1);
            if (c >= 1) atomicAdd(&s_hist[(r << 9) + c], 1);
        }
    }
    __syncthreads();

    // Convert count -> factor, vectorized b128 read/modify/write (owned slots).
    const float l2f = __log2f(1.0f - alpha[0]);
    #pragma unroll
    for (int i = tid; i < ROWS_PER_BLOCK * IMG_W / 4; i += 256) {
        v4i kv = *(v4i*)&s_f4[i];
        v4f fv;
        fv.x = exp2f(l2f * (float)kv.x);                // k==0 -> exactly 1.0f
        fv.y = exp2f(l2f * (float)kv.y);
        fv.z = exp2f(l2f * (float)kv.z);
        fv.w = exp2f(l2f * (float)kv.w);
        s_f4[i] = fv;
    }
    __syncthreads();

    // --- 3. blend + stream out (plain stores) ---
    v4f f0 = s_f4[tid];
    v4f f1 = s_f4[256 + tid];
    v4f f2 = s_f4[512 + tid];
    v4f f3 = s_f4[768 + tid];

    ob[tid]       = blend4(x0, f0);
    ob[256 + tid] = blend4(x1, f1);
    ob[512 + tid] = blend4(x2, f2);
    ob[768 + tid] = blend4(x3, f3);
}

extern "C" void kernel_launch(void* const* d_in, const int* in_sizes, int n_in,
                              void* d_out, int out_size, void* d_ws, size_t ws_size,
                              hipStream_t stream) {
    const float* x      = (const float*)d_in[0];
    const float* alpha  = (const float*)d_in[1];
    const int*   xc     = (const int*)d_in[2];
    const int*   y0     = (const int*)d_in[3];
    const int*   y1_off = (const int*)d_in[4];
    float* out = (float*)d_out;

    int n_streaks = in_sizes[2];

    // out_size = 32*3*512*512 = 25,165,824 scalars; 4096 per block -> 6144 blocks.
    int blocks = out_size / (ROWS_PER_BLOCK * IMG_W);
    rain_fused_kernel<<<blocks, 256, 0, stream>>>(
        (const v4f*)x, alpha, xc, y0, y1_off, (v4f*)out, n_streaks);
}